// Round 20
// baseline (21216.583 us; speedup 1.0000x reference)
//
#include <hip/hip_runtime.h>
#include <hip/hip_bf16.h>
#include <stdint.h>

#define SEQ     512
#define BATCH   32
#define TOKENS  16384   // BATCH*SEQ
#define EMB     1024
#define HEADS   16
#define DEPTH   4
#define K1      1536    // 3*F
#define H3      3072
#define MLPD    4096
#define CH      8192    // tokens per processing chunk (fallback path)
#define NCH     (TOKENS / CH)
#define CB      (CH / SEQ)   // batches per chunk = 16

typedef unsigned short u16;
typedef __attribute__((ext_vector_type(4))) float  f32x4;
typedef __attribute__((ext_vector_type(8))) short  s16x8;
typedef __attribute__((ext_vector_type(4))) u16    u16x4;

#define MFMA_16x16x32_BF16 __builtin_amdgcn_mfma_f32_16x16x32_bf16

__device__ __forceinline__ float bf2f(u16 u) {
  union { float f; uint32_t i; } c; c.i = ((uint32_t)u) << 16; return c.f;
}
__device__ __forceinline__ u16 f2bf(float f) {
  union { float f; uint32_t i; } c; c.f = f;
  uint32_t u = c.i;
  u += 0x7FFFu + ((u >> 16) & 1u);   // RNE
  return (u16)(u >> 16);
}
__device__ __forceinline__ void gll16(const void* g, void* l) {
  __builtin_amdgcn_global_load_lds(
      (const __attribute__((address_space(1))) uint32_t*)g,
      (__attribute__((address_space(3))) uint32_t*)l, 16, 0, 0);
}

// ---------------------------------------------------------------------------
__global__ __launch_bounds__(256)
void fill_kernel(float* __restrict__ out, int n) {
  int i = blockIdx.x * 256 + threadIdx.x;
  if (i < n) out[i] = 1.0e6f;
}

// ---------------------------------------------------------------------------
// Weight transpose + bf16 round:  W[K][N] f32  ->  Wt [N][K] bf16
// ---------------------------------------------------------------------------
__global__ __launch_bounds__(256)
void wtrans_kernel(const float* __restrict__ W, u16* __restrict__ oHi,
                   int K, int N) {
  const int n0 = blockIdx.x * 64, k0 = blockIdx.y * 64;
  __shared__ float tile[64][65];
  const int t = threadIdx.x;
  const int tr = t >> 4, tc4 = (t & 15) * 4;
#pragma unroll
  for (int rr = 0; rr < 4; ++rr) {
    int r = tr + rr * 16;
    const float4 v = *(const float4*)&W[(size_t)(k0 + r) * N + n0 + tc4];
    tile[r][tc4 + 0] = v.x; tile[r][tc4 + 1] = v.y;
    tile[r][tc4 + 2] = v.z; tile[r][tc4 + 3] = v.w;
  }
  __syncthreads();
#pragma unroll
  for (int rr = 0; rr < 4; ++rr) {
    int n = tr + rr * 16;
    u16x4 vh;
#pragma unroll
    for (int j = 0; j < 4; ++j) vh[j] = f2bf(tile[tc4 + j][n]);
    size_t o = (size_t)(n0 + n) * K + k0 + tc4;
    *(u16x4*)&oHi[o] = vh;
  }
}

// ---------------------------------------------------------------------------
// Concat 3 feature streams -> bf16 [M][1536]; pointers pre-offset per chunk.
// ---------------------------------------------------------------------------
__global__ __launch_bounds__(256)
void concat_kernel(const float* __restrict__ i1, const float* __restrict__ i2,
                   const float* __restrict__ tf, u16* __restrict__ fHi) {
  size_t gid = (size_t)blockIdx.x * 256 + threadIdx.x;
  size_t e = gid * 4;
  int m = (int)(e / K1), c = (int)(e % K1);
  const float* src = (c < 512) ? i1 : ((c < 1024) ? i2 : tf);
  const float4 v = *(const float4*)&src[(size_t)m * 512 + (c & 511)];
  u16x4 vh;
  vh[0] = f2bf(v.x); vh[1] = f2bf(v.y); vh[2] = f2bf(v.z); vh[3] = f2bf(v.w);
  *(u16x4*)&fHi[(size_t)m * K1 + c] = vh;
}

// ---------------------------------------------------------------------------
// sincos positional embedding table [512][1024] f32
// ---------------------------------------------------------------------------
__global__ __launch_bounds__(256)
void pos_kernel(float* __restrict__ pos) {
  const int t = blockIdx.x;
#pragma unroll
  for (int p = 0; p < 2; ++p) {
    int d = threadIdx.x + p * 256;              // 0..511
    double omega = pow(10000.0, -(double)d / 512.0);
    double v = (double)t * omega;
    pos[(size_t)t * EMB + d]       = (float)sin(v);
    pos[(size_t)t * EMB + 512 + d] = (float)cos(v);
  }
}

// ---------------------------------------------------------------------------
// LayerNorm over 1024 on bf16 residual; one wave per row, 8 bf16/lane x 2.
// Stats in f32. OUTF=0: bf16 out, 1: f32 out (final).
// ---------------------------------------------------------------------------
template <int OUTF>
__global__ __launch_bounds__(256)
void ln_kernel(const u16* __restrict__ x, const float* __restrict__ scale,
               const float* __restrict__ bias, u16* __restrict__ hHi,
               float* __restrict__ outF) {
  const int w = threadIdx.x >> 6, lane = threadIdx.x & 63;
  const int row = blockIdx.x * 4 + w;
  const u16* xr = x + (size_t)row * EMB;
  float vals[16];
  float s = 0.f, s2 = 0.f;
#pragma unroll
  for (int j = 0; j < 2; ++j) {
    s16x8 raw = *(const s16x8*)&xr[j * 512 + lane * 8];
#pragma unroll
    for (int i = 0; i < 8; ++i) {
      float f = bf2f((u16)raw[i]);
      vals[j * 8 + i] = f;
      s += f; s2 += f * f;
    }
  }
#pragma unroll
  for (int m = 1; m < 64; m <<= 1) {
    s  += __shfl_xor(s, m);
    s2 += __shfl_xor(s2, m);
  }
  const float mu = s * (1.f / EMB);
  const float var = s2 * (1.f / EMB) - mu * mu;
  const float rs = rsqrtf(var + 1e-6f);
#pragma unroll
  for (int j = 0; j < 2; ++j) {
    int c = j * 512 + lane * 8;
    if (OUTF) {
      float4 o0, o1;
      const float4 sc0 = *(const float4*)&scale[c];
      const float4 bi0 = *(const float4*)&bias[c];
      const float4 sc1 = *(const float4*)&scale[c + 4];
      const float4 bi1 = *(const float4*)&bias[c + 4];
      o0.x = (vals[j*8+0] - mu) * rs * sc0.x + bi0.x;
      o0.y = (vals[j*8+1] - mu) * rs * sc0.y + bi0.y;
      o0.z = (vals[j*8+2] - mu) * rs * sc0.z + bi0.z;
      o0.w = (vals[j*8+3] - mu) * rs * sc0.w + bi0.w;
      o1.x = (vals[j*8+4] - mu) * rs * sc1.x + bi1.x;
      o1.y = (vals[j*8+5] - mu) * rs * sc1.y + bi1.y;
      o1.z = (vals[j*8+6] - mu) * rs * sc1.z + bi1.z;
      o1.w = (vals[j*8+7] - mu) * rs * sc1.w + bi1.w;
      *(float4*)&outF[(size_t)row * EMB + c]     = o0;
      *(float4*)&outF[(size_t)row * EMB + c + 4] = o1;
    } else {
      s16x8 vh;
#pragma unroll
      for (int i = 0; i < 8; ++i) {
        float sc = scale[c + i], bi = bias[c + i];
        vh[i] = (short)f2bf((vals[j*8+i] - mu) * rs * sc + bi);
      }
      *(s16x8*)&hHi[(size_t)row * EMB + c] = vh;
    }
  }
}

// ---------------------------------------------------------------------------
// 128x128-tile bf16 GEMM, SINGLE-buffered 16 KiB LDS, 4 waves, max occupancy
// (r19: dropped dbuf per m99/m100+m114 — intra-block dbuf is redundant when
// multi-block overlap exists; 16 KiB LDS admits ~8 blocks/CU at VGPR 56).
// launch_bounds(256,8). Residual stream bf16; GELU via sigmoid identity.
// Swizzle: slot g4 ^ ((r>>1)&3), 0 conflicts measured.
// EPI: 0 = +bias +pos -> bf16 x; 1 = +bias -> bf16 (QKV);
//      2 = +bias +x -> bf16 x; 3 = gelu -> bf16; 4 = +x -> bf16 x.
// ---------------------------------------------------------------------------
template <int EPI>
__global__ __launch_bounds__(256, 8)
void gemm1_kernel(const u16* __restrict__ A, const u16* __restrict__ B,
                  int K, int N, const float* __restrict__ bias,
                  const float* __restrict__ extra, float* __restrict__ outF,
                  u16* __restrict__ outHi) {
  const int tid = threadIdx.x;
  const int lane = tid & 63;
  const int w = tid >> 6;
  const int wm = w >> 1, wn = w & 1;
  const int bm = blockIdx.x * 128, bn = blockIdx.y * 128;
  const int l15 = lane & 15, g4 = lane >> 4;

  __shared__ u16 lds[8192];   // single buf: A 4096 | B 4096 (16 KiB)

  f32x4 acc[4][4];
#pragma unroll
  for (int i = 0; i < 4; ++i)
#pragma unroll
    for (int j = 0; j < 4; ++j) acc[i][j] = f32x4{0.f, 0.f, 0.f, 0.f};

  // ---- hoisted staging: chunks c0=tid, c1=tid+256; r=c>>2; slot=(c&3)^((r>>1)&3)
  const int c0 = tid, c1 = tid + 256;
  const int r0 = c0 >> 2, r1 = c1 >> 2;
  const int sg0 = (c0 & 3) ^ ((r0 >> 1) & 3);
  const int sg1 = (c1 & 3) ^ ((r1 >> 1) & 3);
  const u16* pA0 = A + (size_t)(bm + r0) * K + sg0 * 8;
  const u16* pA1 = A + (size_t)(bm + r1) * K + sg1 * 8;
  const u16* pB0 = B + (size_t)(bn + r0) * K + sg0 * 8;
  const u16* pB1 = B + (size_t)(bn + r1) * K + sg1 * 8;
  u16* dA0 = &lds[c0 * 8];
  u16* dA1 = &lds[c1 * 8];
  u16* dB0 = &lds[4096 + c0 * 8];
  u16* dB1 = &lds[4096 + c1 * 8];

  // ---- hoisted ds_read offsets (u16 index)
  int aIdx[4], bIdx[4];
#pragma unroll
  for (int mi = 0; mi < 4; ++mi) {
    int r = wm * 64 + mi * 16 + l15;
    aIdx[mi] = ((r << 2) | (g4 ^ ((r >> 1) & 3))) * 8;
  }
#pragma unroll
  for (int ni = 0; ni < 4; ++ni) {
    int r = wn * 64 + ni * 16 + l15;
    bIdx[ni] = 4096 + (((r << 2) | (g4 ^ ((r >> 1) & 3))) * 8);
  }

  const int nk = K >> 5;
  for (int kt = 0; kt < nk; ++kt) {
    gll16(pA0, dA0); gll16(pA1, dA1);
    gll16(pB0, dB0); gll16(pB1, dB1);
    pA0 += 32; pA1 += 32; pB0 += 32; pB1 += 32;
    __syncthreads();                         // staging visible to all waves
    s16x8 ah[4], bh[4];
#pragma unroll
    for (int mi = 0; mi < 4; ++mi)
      ah[mi] = *(const s16x8*)&lds[aIdx[mi]];
#pragma unroll
    for (int ni = 0; ni < 4; ++ni)
      bh[ni] = *(const s16x8*)&lds[bIdx[ni]];
#pragma unroll
    for (int mi = 0; mi < 4; ++mi)
#pragma unroll
      for (int ni = 0; ni < 4; ++ni)
        acc[mi][ni] = MFMA_16x16x32_BF16(ah[mi], bh[ni], acc[mi][ni], 0, 0, 0);
    __syncthreads();                         // protect buffer before next stage
  }
  // ---- epilogue: C/D layout row=(lane>>4)*4+reg, col=lane&15 ----
#pragma unroll
  for (int mi = 0; mi < 4; ++mi) {
#pragma unroll
    for (int ni = 0; ni < 4; ++ni) {
      int gc = bn + wn * 64 + ni * 16 + l15;
      float bv = (EPI == 0 || EPI == 1 || EPI == 2) ? bias[gc] : 0.f;
#pragma unroll
      for (int r_ = 0; r_ < 4; ++r_) {
        int gr = bm + wm * 64 + mi * 16 + g4 * 4 + r_;
        float v = acc[mi][ni][r_] + bv;
        size_t o = (size_t)gr * N + gc;
        if (EPI == 0) {
          outHi[o] = f2bf(v + extra[(size_t)(gr & (SEQ - 1)) * EMB + gc]);
        } else if (EPI == 1) {
          outHi[o] = f2bf(v);
        } else if (EPI == 2 || EPI == 4) {
          outHi[o] = f2bf(v + bf2f(outHi[o]));     // bf16 residual RMW
        } else {
          // tanh-approx GELU via sigmoid identity: 0.5v(1+tanh(u)) = v/(1+e^{-2u})
          float u2 = -1.5957691216057308f * (v + 0.044715f * v * v * v);
          float gl = v / (1.f + __expf(u2));
          outHi[o] = f2bf(gl);
        }
      }
    }
  }
}

// ---------------------------------------------------------------------------
// Flash attention fwd. grid (SEQ/64, HEADS, nBatches).
// XCD+temporal remap (r16: FETCH 278->49 MB). VT write rotation. NO max
// subtraction (r18, exact by shift-invariance: scores*0.125 sigma~0.41,
// max ~2.3 << 88 overflow): per-lane linear partial sums, one final reduce.
// ---------------------------------------------------------------------------
__global__ __launch_bounds__(256, 4)
void attn_kernel(const u16* __restrict__ qkv, u16* __restrict__ oHi) {
  const int d = blockIdx.x + (blockIdx.y << 3) + (blockIdx.z << 7);
  const int qb = (d >> 3) & 7;
  const int g = (d & 7) + ((d >> 6) << 3);
  const int h = g & 15, b = g >> 4;
  const int tid = threadIdx.x, lane = tid & 63, w = tid >> 6;
  const int l15 = lane & 15, g4 = lane >> 4;

  __shared__ u16 smem[2048 + 2560 + 2048];
  u16* Klds = smem;
  u16* VT   = smem + 2048;
  u16* Pw   = smem + 2048 + 2560 + w * 512;

  const int q0 = qb * 64 + w * 16;
  const size_t base = (size_t)b * SEQ * H3 + (size_t)h * 64;

  s16x8 qf0, qf1;
  {
    const u16* qp = qkv + base + (size_t)(q0 + l15) * H3 + g4 * 8;
    qf0 = *(const s16x8*)qp;
    qf1 = *(const s16x8*)(qp + 32);
  }

  f32x4 of[4];
#pragma unroll
  for (int n = 0; n < 4; ++n) of[n] = f32x4{0.f, 0.f, 0.f, 0.f};
  float lsum[4] = {0.f, 0.f, 0.f, 0.f};   // per-lane partial denominators

  for (int kt = 0; kt < SEQ; kt += 32) {
    {
      int r = tid >> 3;
      int jj = (tid & 7) ^ (r & 7);
      gll16(qkv + base + (size_t)(kt + r) * H3 + EMB + jj * 8, &Klds[tid * 8]);
    }
    {
      int key = tid >> 3, j = tid & 7;
      s16x8 v = *(const s16x8*)(qkv + base + (size_t)(kt + key) * H3 + 2 * EMB + j * 8);
#pragma unroll
      for (int i = 0; i < 8; ++i) {
        int ii = (i + j) & 7;                       // bank-spread rotation
        VT[(j * 8 + ii) * 40 + key] = (u16)v[ii];
      }
    }
    __syncthreads();
    const int key0 = l15, key1 = 16 + l15;
    s16x8 kf00 = *(const s16x8*)&Klds[key0 * 64 + (((0 + g4) ^ (key0 & 7)) * 8)];
    s16x8 kf01 = *(const s16x8*)&Klds[key0 * 64 + (((4 + g4) ^ (key0 & 7)) * 8)];
    s16x8 kf10 = *(const s16x8*)&Klds[key1 * 64 + (((0 + g4) ^ (key1 & 7)) * 8)];
    s16x8 kf11 = *(const s16x8*)&Klds[key1 * 64 + (((4 + g4) ^ (key1 & 7)) * 8)];
    f32x4 z = f32x4{0.f, 0.f, 0.f, 0.f};
    f32x4 s0 = MFMA_16x16x32_BF16(qf0, kf00, z, 0, 0, 0);
    s0 = MFMA_16x16x32_BF16(qf1, kf01, s0, 0, 0, 0);
    f32x4 s1 = MFMA_16x16x32_BF16(qf0, kf10, z, 0, 0, 0);
    s1 = MFMA_16x16x32_BF16(qf1, kf11, s1, 0, 0, 0);
    // ---- P = exp(s * 0.125) directly (no max; see header comment)
#pragma unroll
    for (int r_ = 0; r_ < 4; ++r_) {
      float p0 = __expf(s0[r_] * 0.125f);
      float p1 = __expf(s1[r_] * 0.125f);
      lsum[r_] += p0 + p1;
      int row = g4 * 4 + r_;
      int sw = (row >> 1) & 3;
      int c0 = (l15 >> 3) ^ sw;
      int c1 = (2 + (l15 >> 3)) ^ sw;
      Pw[(row * 4 + c0) * 8 + (l15 & 7)] = f2bf(p0);
      Pw[(row * 4 + c1) * 8 + (l15 & 7)] = f2bf(p1);
    }
    {
      int pchunk = (l15 << 2) | (g4 ^ ((l15 >> 1) & 3));
      s16x8 pf = *(const s16x8*)&Pw[pchunk * 8];
#pragma unroll
      for (int n = 0; n < 4; ++n) {
        s16x8 vf = *(const s16x8*)&VT[(n * 16 + l15) * 40 + g4 * 8];
        of[n] = MFMA_16x16x32_BF16(pf, vf, of[n], 0, 0, 0);
      }
    }
    __syncthreads();
  }
  // ---- final: reduce denominators across the 16 lanes of each row group
#pragma unroll
  for (int r_ = 0; r_ < 4; ++r_) {
    lsum[r_] += __shfl_xor(lsum[r_], 1);
    lsum[r_] += __shfl_xor(lsum[r_], 2);
    lsum[r_] += __shfl_xor(lsum[r_], 4);
    lsum[r_] += __shfl_xor(lsum[r_], 8);
    float inv = 1.f / lsum[r_];
    int qrow = q0 + g4 * 4 + r_;
    size_t ob = (size_t)(b * SEQ + qrow) * EMB + h * 64;
#pragma unroll
    for (int n = 0; n < 4; ++n)
      oHi[ob + n * 16 + l15] = f2bf(of[n][r_] * inv);
  }
}

// ---------------------------------------------------------------------------
extern "C" void kernel_launch(void* const* d_in, const int* in_sizes, int n_in,
                              void* d_out, int out_size, void* d_ws, size_t ws_size,
                              hipStream_t stream) {
  const float* image1     = (const float*)d_in[0];
  const float* image2     = (const float*)d_in[1];
  const float* text_feat  = (const float*)d_in[2];
  const float* mlp_kernel = (const float*)d_in[3];
  const float* mlp_bias   = (const float*)d_in[4];
  const float* ln1_scale  = (const float*)d_in[5];
  const float* ln1_bias   = (const float*)d_in[6];
  const float* qkv_kernel = (const float*)d_in[7];
  const float* qkv_bias   = (const float*)d_in[8];
  const float* proj_kernel= (const float*)d_in[9];
  const float* proj_bias  = (const float*)d_in[10];
  const float* ln2_scale  = (const float*)d_in[11];
  const float* ln2_bias   = (const float*)d_in[12];
  const float* fc1_kernel = (const float*)d_in[13];
  const float* fc2_kernel = (const float*)d_in[14];
  const float* lnf_scale  = (const float*)d_in[15];
  const float* lnf_bias   = (const float*)d_in[16];

  // ---- workspace: x is bf16 (32 MiB). FULL big=128 MiB or CHUNK 64 MiB.
  char* ws = (char*)d_ws;
  size_t off = 0;
  auto take = [&](size_t bytes) { size_t o = off; off += (bytes + 255) & ~(size_t)255; return o; };
  const size_t oX    = take((size_t)TOKENS * EMB * 2);            // 32 MiB residual bf16
  const size_t oPos  = take((size_t)SEQ * EMB * 4);               //  2 MiB
  const size_t oSh   = take((size_t)TOKENS * EMB * 2);            // 32 MiB: hC/oA/hFull
  const size_t oBig  = off;                                        // big region start
  const size_t fullNeed  = oBig + (((size_t)TOKENS * MLPD * 2 + 255) & ~(size_t)255)
                          + 16 * 1024 * 1024;
  const size_t chunkNeed = oBig + (((size_t)CH * MLPD * 2 + 255) & ~(size_t)255)
                          + 16 * 1024 * 1024;
  const bool FULL = (fullNeed <= ws_size);
  const size_t bigBytes = FULL ? (((size_t)TOKENS * MLPD * 2 + 255) & ~(size_t)255)
                               : (((size_t)CH * MLPD * 2 + 255) & ~(size_t)255);
  const size_t oWbuf = oBig + bigBytes;
  if (!FULL && chunkNeed > ws_size) {  // diagnostic: absmax ~1e6 => ws too small
    fill_kernel<<<(out_size + 255) / 256, 256, 0, stream>>>((float*)d_out, out_size);
    return;
  }

  u16* x     = (u16*)(ws + oX);
  float* pos = (float*)(ws + oPos);
  u16* shrd  = (u16*)(ws + oSh);   // LN1-out | attn-out | LN2-out (time-shared)
  u16* big   = (u16*)(ws + oBig);
  u16* wbuf  = (u16*)(ws + oWbuf);
  u16* wq  = wbuf;                              // 6 MiB [3072][1024]
  u16* wp  = wbuf + (size_t)3 * 1024 * 1024;    // 2 MiB [1024][1024]
  u16* wf1 = wbuf;                              // 8 MiB [4096][1024]
  u16* wf2 = wbuf + (size_t)4 * 1024 * 1024;    // 8 MiB [1024][4096]
  u16* w1t = wbuf;                              // 3 MiB [1024][1536]

  pos_kernel<<<SEQ, 256, 0, stream>>>(pos);

  // ---- MLP-in: x = bf16(concat(feats) @ W1 + b + pos)
  wtrans_kernel<<<dim3(EMB / 64, K1 / 64), 256, 0, stream>>>(mlp_kernel, w1t, K1, EMB);
  if (FULL) {
    concat_kernel<<<TOKENS * K1 / 1024, 256, 0, stream>>>(image1, image2, text_feat, big);
    gemm1_kernel<0><<<dim3(TOKENS / 128, EMB / 128), 256, 0, stream>>>(
        big, w1t, K1, EMB, mlp_bias, pos, nullptr, x);
  } else {
    for (int c = 0; c < NCH; ++c) {
      const size_t fo = (size_t)c * CH * 512;
      concat_kernel<<<CH * K1 / 1024, 256, 0, stream>>>(image1 + fo, image2 + fo, text_feat + fo, big);
      gemm1_kernel<0><<<dim3(CH / 128, EMB / 128), 256, 0, stream>>>(
          big, w1t, K1, EMB, mlp_bias, pos, nullptr, x + (size_t)c * CH * EMB);
    }
  }

  for (int i = 0; i < DEPTH; ++i) {
    wtrans_kernel<<<dim3(H3 / 64, EMB / 64), 256, 0, stream>>>(
        qkv_kernel + (size_t)i * EMB * H3, wq, EMB, H3);
    wtrans_kernel<<<dim3(EMB / 64, EMB / 64), 256, 0, stream>>>(
        proj_kernel + (size_t)i * EMB * EMB, wp, EMB, EMB);
    if (FULL) {
      ln_kernel<0><<<TOKENS / 4, 256, 0, stream>>>(x, ln1_scale + i * EMB, ln1_bias + i * EMB,
                                                   shrd, nullptr);
      gemm1_kernel<1><<<dim3(TOKENS / 128, H3 / 128), 256, 0, stream>>>(
          shrd, wq, EMB, H3, qkv_bias + i * H3, nullptr, nullptr, big);
      attn_kernel<<<dim3(SEQ / 64, HEADS, BATCH), 256, 0, stream>>>(big, shrd);
    } else {
      u16* hC = big + (size_t)CH * H3;
      for (int c = 0; c < NCH; ++c) {
        ln_kernel<0><<<CH / 4, 256, 0, stream>>>(x + (size_t)c * CH * EMB,
                                                 ln1_scale + i * EMB, ln1_bias + i * EMB,
                                                 hC, nullptr);
        gemm1_kernel<1><<<dim3(CH / 128, H3 / 128), 256, 0, stream>>>(
            hC, wq, EMB, H3, qkv_bias + i * H3, nullptr, nullptr, big);
        attn_kernel<<<dim3(SEQ / 64, HEADS, CB), 256, 0, stream>>>(big, shrd + (size_t)c * CH * EMB);
      }
    }
    gemm1_kernel<2><<<dim3(TOKENS / 128, EMB / 128), 256, 0, stream>>>(
        shrd, wp, EMB, EMB, proj_bias + i * EMB, nullptr, nullptr, x);

    // ---- MLP: LN2 -> shrd (once); fc1 -> big; fc2 accumulates into bf16 x
    ln_kernel<0><<<TOKENS / 4, 256, 0, stream>>>(x, ln2_scale + i * EMB, ln2_bias + i * EMB,
                                                 shrd, nullptr);
    wtrans_kernel<<<dim3(MLPD / 64, EMB / 64), 256, 0, stream>>>(
        fc1_kernel + (size_t)i * EMB * MLPD, wf1, EMB, MLPD);
    wtrans_kernel<<<dim3(EMB / 64, MLPD / 64), 256, 0, stream>>>(
        fc2_kernel + (size_t)i * MLPD * EMB, wf2, MLPD, EMB);
    if (FULL) {
      gemm1_kernel<3><<<dim3(TOKENS / 128, MLPD / 128), 256, 0, stream>>>(
          shrd, wf1, EMB, MLPD, nullptr, nullptr, nullptr, big);
      gemm1_kernel<4><<<dim3(TOKENS / 128, EMB / 128), 256, 0, stream>>>(
          big, wf2, MLPD, EMB, nullptr, nullptr, nullptr, x);
    } else {
      for (int c = 0; c < NCH; ++c) {
        gemm1_kernel<3><<<dim3(CH / 128, MLPD / 128), 256, 0, stream>>>(
            shrd + (size_t)c * CH * EMB, wf1, EMB, MLPD, nullptr, nullptr, nullptr, big);
        gemm1_kernel<4><<<dim3(CH / 128, EMB / 128), 256, 0, stream>>>(
            big, wf2, MLPD, EMB, nullptr, nullptr, nullptr, x + (size_t)c * CH * EMB);
      }
    }
  }
  ln_kernel<1><<<TOKENS / 4, 256, 0, stream>>>(x, lnf_scale, lnf_bias,
                                               nullptr, (float*)d_out);
}

// Round 21
// 2751.917 us; speedup vs baseline: 7.7097x; 7.7097x over previous
//
#include <hip/hip_runtime.h>
#include <hip/hip_bf16.h>
#include <stdint.h>

#define SEQ     512
#define BATCH   32
#define TOKENS  16384   // BATCH*SEQ
#define EMB     1024
#define HEADS   16
#define DEPTH   4
#define K1      1536    // 3*F
#define H3      3072
#define MLPD    4096
#define CH      8192    // tokens per processing chunk (fallback path)
#define NCH     (TOKENS / CH)
#define CB      (CH / SEQ)   // batches per chunk = 16

typedef unsigned short u16;
typedef __attribute__((ext_vector_type(4))) float  f32x4;
typedef __attribute__((ext_vector_type(8))) short  s16x8;
typedef __attribute__((ext_vector_type(4))) u16    u16x4;

#define MFMA_16x16x32_BF16 __builtin_amdgcn_mfma_f32_16x16x32_bf16

__device__ __forceinline__ float bf2f(u16 u) {
  union { float f; uint32_t i; } c; c.i = ((uint32_t)u) << 16; return c.f;
}
__device__ __forceinline__ u16 f2bf(float f) {
  union { float f; uint32_t i; } c; c.f = f;
  uint32_t u = c.i;
  u += 0x7FFFu + ((u >> 16) & 1u);   // RNE
  return (u16)(u >> 16);
}
__device__ __forceinline__ void gll16(const void* g, void* l) {
  __builtin_amdgcn_global_load_lds(
      (const __attribute__((address_space(1))) uint32_t*)g,
      (__attribute__((address_space(3))) uint32_t*)l, 16, 0, 0);
}

// ---------------------------------------------------------------------------
__global__ __launch_bounds__(256)
void fill_kernel(float* __restrict__ out, int n) {
  int i = blockIdx.x * 256 + threadIdx.x;
  if (i < n) out[i] = 1.0e6f;
}

// ---------------------------------------------------------------------------
// Weight transpose + bf16 round:  W[K][N] f32  ->  Wt [N][K] bf16
// ---------------------------------------------------------------------------
__global__ __launch_bounds__(256)
void wtrans_kernel(const float* __restrict__ W, u16* __restrict__ oHi,
                   int K, int N) {
  const int n0 = blockIdx.x * 64, k0 = blockIdx.y * 64;
  __shared__ float tile[64][65];
  const int t = threadIdx.x;
  const int tr = t >> 4, tc4 = (t & 15) * 4;
#pragma unroll
  for (int rr = 0; rr < 4; ++rr) {
    int r = tr + rr * 16;
    const float4 v = *(const float4*)&W[(size_t)(k0 + r) * N + n0 + tc4];
    tile[r][tc4 + 0] = v.x; tile[r][tc4 + 1] = v.y;
    tile[r][tc4 + 2] = v.z; tile[r][tc4 + 3] = v.w;
  }
  __syncthreads();
#pragma unroll
  for (int rr = 0; rr < 4; ++rr) {
    int n = tr + rr * 16;
    u16x4 vh;
#pragma unroll
    for (int j = 0; j < 4; ++j) vh[j] = f2bf(tile[tc4 + j][n]);
    size_t o = (size_t)(n0 + n) * K + k0 + tc4;
    *(u16x4*)&oHi[o] = vh;
  }
}

// ---------------------------------------------------------------------------
// Concat 3 feature streams -> bf16 [M][1536]; pointers pre-offset per chunk.
// ---------------------------------------------------------------------------
__global__ __launch_bounds__(256)
void concat_kernel(const float* __restrict__ i1, const float* __restrict__ i2,
                   const float* __restrict__ tf, u16* __restrict__ fHi) {
  size_t gid = (size_t)blockIdx.x * 256 + threadIdx.x;
  size_t e = gid * 4;
  int m = (int)(e / K1), c = (int)(e % K1);
  const float* src = (c < 512) ? i1 : ((c < 1024) ? i2 : tf);
  const float4 v = *(const float4*)&src[(size_t)m * 512 + (c & 511)];
  u16x4 vh;
  vh[0] = f2bf(v.x); vh[1] = f2bf(v.y); vh[2] = f2bf(v.z); vh[3] = f2bf(v.w);
  *(u16x4*)&fHi[(size_t)m * K1 + c] = vh;
}

// ---------------------------------------------------------------------------
// sincos positional embedding table [512][1024] f32
// ---------------------------------------------------------------------------
__global__ __launch_bounds__(256)
void pos_kernel(float* __restrict__ pos) {
  const int t = blockIdx.x;
#pragma unroll
  for (int p = 0; p < 2; ++p) {
    int d = threadIdx.x + p * 256;              // 0..511
    double omega = pow(10000.0, -(double)d / 512.0);
    double v = (double)t * omega;
    pos[(size_t)t * EMB + d]       = (float)sin(v);
    pos[(size_t)t * EMB + 512 + d] = (float)cos(v);
  }
}

// ---------------------------------------------------------------------------
// LayerNorm over 1024 on bf16 residual; one wave per row, 8 bf16/lane x 2.
// Stats in f32. OUTF=0: bf16 out, 1: f32 out (final).
// ---------------------------------------------------------------------------
template <int OUTF>
__global__ __launch_bounds__(256)
void ln_kernel(const u16* __restrict__ x, const float* __restrict__ scale,
               const float* __restrict__ bias, u16* __restrict__ hHi,
               float* __restrict__ outF) {
  const int w = threadIdx.x >> 6, lane = threadIdx.x & 63;
  const int row = blockIdx.x * 4 + w;
  const u16* xr = x + (size_t)row * EMB;
  float vals[16];
  float s = 0.f, s2 = 0.f;
#pragma unroll
  for (int j = 0; j < 2; ++j) {
    s16x8 raw = *(const s16x8*)&xr[j * 512 + lane * 8];
#pragma unroll
    for (int i = 0; i < 8; ++i) {
      float f = bf2f((u16)raw[i]);
      vals[j * 8 + i] = f;
      s += f; s2 += f * f;
    }
  }
#pragma unroll
  for (int m = 1; m < 64; m <<= 1) {
    s  += __shfl_xor(s, m);
    s2 += __shfl_xor(s2, m);
  }
  const float mu = s * (1.f / EMB);
  const float var = s2 * (1.f / EMB) - mu * mu;
  const float rs = rsqrtf(var + 1e-6f);
#pragma unroll
  for (int j = 0; j < 2; ++j) {
    int c = j * 512 + lane * 8;
    if (OUTF) {
      float4 o0, o1;
      const float4 sc0 = *(const float4*)&scale[c];
      const float4 bi0 = *(const float4*)&bias[c];
      const float4 sc1 = *(const float4*)&scale[c + 4];
      const float4 bi1 = *(const float4*)&bias[c + 4];
      o0.x = (vals[j*8+0] - mu) * rs * sc0.x + bi0.x;
      o0.y = (vals[j*8+1] - mu) * rs * sc0.y + bi0.y;
      o0.z = (vals[j*8+2] - mu) * rs * sc0.z + bi0.z;
      o0.w = (vals[j*8+3] - mu) * rs * sc0.w + bi0.w;
      o1.x = (vals[j*8+4] - mu) * rs * sc1.x + bi1.x;
      o1.y = (vals[j*8+5] - mu) * rs * sc1.y + bi1.y;
      o1.z = (vals[j*8+6] - mu) * rs * sc1.z + bi1.z;
      o1.w = (vals[j*8+7] - mu) * rs * sc1.w + bi1.w;
      *(float4*)&outF[(size_t)row * EMB + c]     = o0;
      *(float4*)&outF[(size_t)row * EMB + c + 4] = o1;
    } else {
      s16x8 vh;
#pragma unroll
      for (int i = 0; i < 8; ++i) {
        float sc = scale[c + i], bi = bias[c + i];
        vh[i] = (short)f2bf((vals[j*8+i] - mu) * rs * sc + bi);
      }
      *(s16x8*)&hHi[(size_t)row * EMB + c] = vh;
    }
  }
}

// ---------------------------------------------------------------------------
// 128x128-tile bf16 GEMM, 2-phase dbuf, 32 KiB LDS, 4 waves, multi-block
// (r18 config — measured best 712 TF; r20's (256,8) single-buffer forced
// VGPR 32 -> full spill, 6.7x regression, reverted). Residual bf16; GELU via
// sigmoid identity. Swizzle: slot g4 ^ ((r>>1)&3), 0 conflicts measured.
// EPI: 0 = +bias +pos -> bf16 x; 1 = +bias -> bf16 (QKV);
//      2 = +bias +x -> bf16 x; 3 = gelu -> bf16; 4 = +x -> bf16 x.
// ---------------------------------------------------------------------------
template <int EPI>
__global__ __launch_bounds__(256, 4)
void gemm1_kernel(const u16* __restrict__ A, const u16* __restrict__ B,
                  int K, int N, const float* __restrict__ bias,
                  const float* __restrict__ extra, float* __restrict__ outF,
                  u16* __restrict__ outHi) {
  const int tid = threadIdx.x;
  const int lane = tid & 63;
  const int w = tid >> 6;
  const int wm = w >> 1, wn = w & 1;
  const int bm = blockIdx.x * 128, bn = blockIdx.y * 128;
  const int l15 = lane & 15, g4 = lane >> 4;

  __shared__ u16 lds[16384];   // 2 bufs x (A 4096 | B 4096) u16

  f32x4 acc[4][4];
#pragma unroll
  for (int i = 0; i < 4; ++i)
#pragma unroll
    for (int j = 0; j < 4; ++j) acc[i][j] = f32x4{0.f, 0.f, 0.f, 0.f};

  // ---- hoisted staging: chunks c0=tid, c1=tid+256; r=c>>2; slot=(c&3)^((r>>1)&3)
  const int c0 = tid, c1 = tid + 256;
  const int r0 = c0 >> 2, r1 = c1 >> 2;
  const int sg0 = (c0 & 3) ^ ((r0 >> 1) & 3);
  const int sg1 = (c1 & 3) ^ ((r1 >> 1) & 3);
  const u16* pA0 = A + (size_t)(bm + r0) * K + sg0 * 8;
  const u16* pA1 = A + (size_t)(bm + r1) * K + sg1 * 8;
  const u16* pB0 = B + (size_t)(bn + r0) * K + sg0 * 8;
  const u16* pB1 = B + (size_t)(bn + r1) * K + sg1 * 8;
  u16* dA0 = &lds[c0 * 8];
  u16* dA1 = &lds[c1 * 8];
  u16* dB0 = &lds[4096 + c0 * 8];
  u16* dB1 = &lds[4096 + c1 * 8];

  // ---- hoisted ds_read offsets (u16 index)
  int aIdx[4], bIdx[4];
#pragma unroll
  for (int mi = 0; mi < 4; ++mi) {
    int r = wm * 64 + mi * 16 + l15;
    aIdx[mi] = ((r << 2) | (g4 ^ ((r >> 1) & 3))) * 8;
  }
#pragma unroll
  for (int ni = 0; ni < 4; ++ni) {
    int r = wn * 64 + ni * 16 + l15;
    bIdx[ni] = 4096 + (((r << 2) | (g4 ^ ((r >> 1) & 3))) * 8);
  }

  const int nk = K >> 5;
  gll16(pA0, dA0); gll16(pA1, dA1);
  gll16(pB0, dB0); gll16(pB1, dB1);
  pA0 += 32; pA1 += 32; pB0 += 32; pB1 += 32;
  for (int kt = 0; kt < nk; ++kt) {
    const int ab = (kt & 1) * 8192;
    const int nb = ((kt & 1) ^ 1) * 8192;
    __syncthreads();
    if (kt + 1 < nk) {
      gll16(pA0, dA0 + nb); gll16(pA1, dA1 + nb);
      gll16(pB0, dB0 + nb); gll16(pB1, dB1 + nb);
      pA0 += 32; pA1 += 32; pB0 += 32; pB1 += 32;
    }
    s16x8 ah[4], bh[4];
#pragma unroll
    for (int mi = 0; mi < 4; ++mi)
      ah[mi] = *(const s16x8*)&lds[ab + aIdx[mi]];
#pragma unroll
    for (int ni = 0; ni < 4; ++ni)
      bh[ni] = *(const s16x8*)&lds[ab + bIdx[ni]];
#pragma unroll
    for (int mi = 0; mi < 4; ++mi)
#pragma unroll
      for (int ni = 0; ni < 4; ++ni)
        acc[mi][ni] = MFMA_16x16x32_BF16(ah[mi], bh[ni], acc[mi][ni], 0, 0, 0);
  }
  // ---- epilogue: C/D layout row=(lane>>4)*4+reg, col=lane&15 ----
#pragma unroll
  for (int mi = 0; mi < 4; ++mi) {
#pragma unroll
    for (int ni = 0; ni < 4; ++ni) {
      int gc = bn + wn * 64 + ni * 16 + l15;
      float bv = (EPI == 0 || EPI == 1 || EPI == 2) ? bias[gc] : 0.f;
#pragma unroll
      for (int r_ = 0; r_ < 4; ++r_) {
        int gr = bm + wm * 64 + mi * 16 + g4 * 4 + r_;
        float v = acc[mi][ni][r_] + bv;
        size_t o = (size_t)gr * N + gc;
        if (EPI == 0) {
          outHi[o] = f2bf(v + extra[(size_t)(gr & (SEQ - 1)) * EMB + gc]);
        } else if (EPI == 1) {
          outHi[o] = f2bf(v);
        } else if (EPI == 2 || EPI == 4) {
          outHi[o] = f2bf(v + bf2f(outHi[o]));     // bf16 residual RMW
        } else {
          // tanh-approx GELU via sigmoid identity: 0.5v(1+tanh(u)) = v/(1+e^{-2u})
          float u2 = -1.5957691216057308f * (v + 0.044715f * v * v * v);
          float gl = v / (1.f + __expf(u2));
          outHi[o] = f2bf(gl);
        }
      }
    }
  }
}

// ---------------------------------------------------------------------------
// Flash attention fwd. grid (SEQ/64, HEADS, nBatches).
// XCD+temporal remap (r16: FETCH 278->49 MB). VT write rotation. NO max
// subtraction (r18, exact by shift-invariance: scores*0.125 sigma~0.41,
// max ~2.3 << 88 overflow): per-lane linear partial sums, one final reduce.
// ---------------------------------------------------------------------------
__global__ __launch_bounds__(256, 4)
void attn_kernel(const u16* __restrict__ qkv, u16* __restrict__ oHi) {
  const int d = blockIdx.x + (blockIdx.y << 3) + (blockIdx.z << 7);
  const int qb = (d >> 3) & 7;
  const int g = (d & 7) + ((d >> 6) << 3);
  const int h = g & 15, b = g >> 4;
  const int tid = threadIdx.x, lane = tid & 63, w = tid >> 6;
  const int l15 = lane & 15, g4 = lane >> 4;

  __shared__ u16 smem[2048 + 2560 + 2048];
  u16* Klds = smem;
  u16* VT   = smem + 2048;
  u16* Pw   = smem + 2048 + 2560 + w * 512;

  const int q0 = qb * 64 + w * 16;
  const size_t base = (size_t)b * SEQ * H3 + (size_t)h * 64;

  s16x8 qf0, qf1;
  {
    const u16* qp = qkv + base + (size_t)(q0 + l15) * H3 + g4 * 8;
    qf0 = *(const s16x8*)qp;
    qf1 = *(const s16x8*)(qp + 32);
  }

  f32x4 of[4];
#pragma unroll
  for (int n = 0; n < 4; ++n) of[n] = f32x4{0.f, 0.f, 0.f, 0.f};
  float lsum[4] = {0.f, 0.f, 0.f, 0.f};   // per-lane partial denominators

  for (int kt = 0; kt < SEQ; kt += 32) {
    {
      int r = tid >> 3;
      int jj = (tid & 7) ^ (r & 7);
      gll16(qkv + base + (size_t)(kt + r) * H3 + EMB + jj * 8, &Klds[tid * 8]);
    }
    {
      int key = tid >> 3, j = tid & 7;
      s16x8 v = *(const s16x8*)(qkv + base + (size_t)(kt + key) * H3 + 2 * EMB + j * 8);
#pragma unroll
      for (int i = 0; i < 8; ++i) {
        int ii = (i + j) & 7;                       // bank-spread rotation
        VT[(j * 8 + ii) * 40 + key] = (u16)v[ii];
      }
    }
    __syncthreads();
    const int key0 = l15, key1 = 16 + l15;
    s16x8 kf00 = *(const s16x8*)&Klds[key0 * 64 + (((0 + g4) ^ (key0 & 7)) * 8)];
    s16x8 kf01 = *(const s16x8*)&Klds[key0 * 64 + (((4 + g4) ^ (key0 & 7)) * 8)];
    s16x8 kf10 = *(const s16x8*)&Klds[key1 * 64 + (((0 + g4) ^ (key1 & 7)) * 8)];
    s16x8 kf11 = *(const s16x8*)&Klds[key1 * 64 + (((4 + g4) ^ (key1 & 7)) * 8)];
    f32x4 z = f32x4{0.f, 0.f, 0.f, 0.f};
    f32x4 s0 = MFMA_16x16x32_BF16(qf0, kf00, z, 0, 0, 0);
    s0 = MFMA_16x16x32_BF16(qf1, kf01, s0, 0, 0, 0);
    f32x4 s1 = MFMA_16x16x32_BF16(qf0, kf10, z, 0, 0, 0);
    s1 = MFMA_16x16x32_BF16(qf1, kf11, s1, 0, 0, 0);
    // ---- P = exp(s * 0.125) directly (no max; see header comment)
#pragma unroll
    for (int r_ = 0; r_ < 4; ++r_) {
      float p0 = __expf(s0[r_] * 0.125f);
      float p1 = __expf(s1[r_] * 0.125f);
      lsum[r_] += p0 + p1;
      int row = g4 * 4 + r_;
      int sw = (row >> 1) & 3;
      int c0 = (l15 >> 3) ^ sw;
      int c1 = (2 + (l15 >> 3)) ^ sw;
      Pw[(row * 4 + c0) * 8 + (l15 & 7)] = f2bf(p0);
      Pw[(row * 4 + c1) * 8 + (l15 & 7)] = f2bf(p1);
    }
    {
      int pchunk = (l15 << 2) | (g4 ^ ((l15 >> 1) & 3));
      s16x8 pf = *(const s16x8*)&Pw[pchunk * 8];
#pragma unroll
      for (int n = 0; n < 4; ++n) {
        s16x8 vf = *(const s16x8*)&VT[(n * 16 + l15) * 40 + g4 * 8];
        of[n] = MFMA_16x16x32_BF16(pf, vf, of[n], 0, 0, 0);
      }
    }
    __syncthreads();
  }
  // ---- final: reduce denominators across the 16 lanes of each row group
#pragma unroll
  for (int r_ = 0; r_ < 4; ++r_) {
    lsum[r_] += __shfl_xor(lsum[r_], 1);
    lsum[r_] += __shfl_xor(lsum[r_], 2);
    lsum[r_] += __shfl_xor(lsum[r_], 4);
    lsum[r_] += __shfl_xor(lsum[r_], 8);
    float inv = 1.f / lsum[r_];
    int qrow = q0 + g4 * 4 + r_;
    size_t ob = (size_t)(b * SEQ + qrow) * EMB + h * 64;
#pragma unroll
    for (int n = 0; n < 4; ++n)
      oHi[ob + n * 16 + l15] = f2bf(of[n][r_] * inv);
  }
}

// ---------------------------------------------------------------------------
extern "C" void kernel_launch(void* const* d_in, const int* in_sizes, int n_in,
                              void* d_out, int out_size, void* d_ws, size_t ws_size,
                              hipStream_t stream) {
  const float* image1     = (const float*)d_in[0];
  const float* image2     = (const float*)d_in[1];
  const float* text_feat  = (const float*)d_in[2];
  const float* mlp_kernel = (const float*)d_in[3];
  const float* mlp_bias   = (const float*)d_in[4];
  const float* ln1_scale  = (const float*)d_in[5];
  const float* ln1_bias   = (const float*)d_in[6];
  const float* qkv_kernel = (const float*)d_in[7];
  const float* qkv_bias   = (const float*)d_in[8];
  const float* proj_kernel= (const float*)d_in[9];
  const float* proj_bias  = (const float*)d_in[10];
  const float* ln2_scale  = (const float*)d_in[11];
  const float* ln2_bias   = (const float*)d_in[12];
  const float* fc1_kernel = (const float*)d_in[13];
  const float* fc2_kernel = (const float*)d_in[14];
  const float* lnf_scale  = (const float*)d_in[15];
  const float* lnf_bias   = (const float*)d_in[16];

  // ---- workspace: x is bf16 (32 MiB). FULL big=128 MiB or CHUNK 64 MiB.
  char* ws = (char*)d_ws;
  size_t off = 0;
  auto take = [&](size_t bytes) { size_t o = off; off += (bytes + 255) & ~(size_t)255; return o; };
  const size_t oX    = take((size_t)TOKENS * EMB * 2);            // 32 MiB residual bf16
  const size_t oPos  = take((size_t)SEQ * EMB * 4);               //  2 MiB
  const size_t oSh   = take((size_t)TOKENS * EMB * 2);            // 32 MiB: hC/oA/hFull
  const size_t oBig  = off;                                        // big region start
  const size_t fullNeed  = oBig + (((size_t)TOKENS * MLPD * 2 + 255) & ~(size_t)255)
                          + 16 * 1024 * 1024;
  const size_t chunkNeed = oBig + (((size_t)CH * MLPD * 2 + 255) & ~(size_t)255)
                          + 16 * 1024 * 1024;
  const bool FULL = (fullNeed <= ws_size);
  const size_t bigBytes = FULL ? (((size_t)TOKENS * MLPD * 2 + 255) & ~(size_t)255)
                               : (((size_t)CH * MLPD * 2 + 255) & ~(size_t)255);
  const size_t oWbuf = oBig + bigBytes;
  if (!FULL && chunkNeed > ws_size) {  // diagnostic: absmax ~1e6 => ws too small
    fill_kernel<<<(out_size + 255) / 256, 256, 0, stream>>>((float*)d_out, out_size);
    return;
  }

  u16* x     = (u16*)(ws + oX);
  float* pos = (float*)(ws + oPos);
  u16* shrd  = (u16*)(ws + oSh);   // LN1-out | attn-out | LN2-out (time-shared)
  u16* big   = (u16*)(ws + oBig);
  u16* wbuf  = (u16*)(ws + oWbuf);
  u16* wq  = wbuf;                              // 6 MiB [3072][1024]
  u16* wp  = wbuf + (size_t)3 * 1024 * 1024;    // 2 MiB [1024][1024]
  u16* wf1 = wbuf;                              // 8 MiB [4096][1024]
  u16* wf2 = wbuf + (size_t)4 * 1024 * 1024;    // 8 MiB [1024][4096]
  u16* w1t = wbuf;                              // 3 MiB [1024][1536]

  pos_kernel<<<SEQ, 256, 0, stream>>>(pos);

  // ---- MLP-in: x = bf16(concat(feats) @ W1 + b + pos)
  wtrans_kernel<<<dim3(EMB / 64, K1 / 64), 256, 0, stream>>>(mlp_kernel, w1t, K1, EMB);
  if (FULL) {
    concat_kernel<<<TOKENS * K1 / 1024, 256, 0, stream>>>(image1, image2, text_feat, big);
    gemm1_kernel<0><<<dim3(TOKENS / 128, EMB / 128), 256, 0, stream>>>(
        big, w1t, K1, EMB, mlp_bias, pos, nullptr, x);
  } else {
    for (int c = 0; c < NCH; ++c) {
      const size_t fo = (size_t)c * CH * 512;
      concat_kernel<<<CH * K1 / 1024, 256, 0, stream>>>(image1 + fo, image2 + fo, text_feat + fo, big);
      gemm1_kernel<0><<<dim3(CH / 128, EMB / 128), 256, 0, stream>>>(
          big, w1t, K1, EMB, mlp_bias, pos, nullptr, x + (size_t)c * CH * EMB);
    }
  }

  for (int i = 0; i < DEPTH; ++i) {
    wtrans_kernel<<<dim3(H3 / 64, EMB / 64), 256, 0, stream>>>(
        qkv_kernel + (size_t)i * EMB * H3, wq, EMB, H3);
    wtrans_kernel<<<dim3(EMB / 64, EMB / 64), 256, 0, stream>>>(
        proj_kernel + (size_t)i * EMB * EMB, wp, EMB, EMB);
    if (FULL) {
      ln_kernel<0><<<TOKENS / 4, 256, 0, stream>>>(x, ln1_scale + i * EMB, ln1_bias + i * EMB,
                                                   shrd, nullptr);
      gemm1_kernel<1><<<dim3(TOKENS / 128, H3 / 128), 256, 0, stream>>>(
          shrd, wq, EMB, H3, qkv_bias + i * H3, nullptr, nullptr, big);
      attn_kernel<<<dim3(SEQ / 64, HEADS, BATCH), 256, 0, stream>>>(big, shrd);
    } else {
      u16* hC = big + (size_t)CH * H3;
      for (int c = 0; c < NCH; ++c) {
        ln_kernel<0><<<CH / 4, 256, 0, stream>>>(x + (size_t)c * CH * EMB,
                                                 ln1_scale + i * EMB, ln1_bias + i * EMB,
                                                 hC, nullptr);
        gemm1_kernel<1><<<dim3(CH / 128, H3 / 128), 256, 0, stream>>>(
            hC, wq, EMB, H3, qkv_bias + i * H3, nullptr, nullptr, big);
        attn_kernel<<<dim3(SEQ / 64, HEADS, CB), 256, 0, stream>>>(big, shrd + (size_t)c * CH * EMB);
      }
    }
    gemm1_kernel<2><<<dim3(TOKENS / 128, EMB / 128), 256, 0, stream>>>(
        shrd, wp, EMB, EMB, proj_bias + i * EMB, nullptr, nullptr, x);

    // ---- MLP: LN2 -> shrd (once); fc1 -> big; fc2 accumulates into bf16 x
    ln_kernel<0><<<TOKENS / 4, 256, 0, stream>>>(x, ln2_scale + i * EMB, ln2_bias + i * EMB,
                                                 shrd, nullptr);
    wtrans_kernel<<<dim3(MLPD / 64, EMB / 64), 256, 0, stream>>>(
        fc1_kernel + (size_t)i * EMB * MLPD, wf1, EMB, MLPD);
    wtrans_kernel<<<dim3(EMB / 64, MLPD / 64), 256, 0, stream>>>(
        fc2_kernel + (size_t)i * MLPD * EMB, wf2, MLPD, EMB);
    if (FULL) {
      gemm1_kernel<3><<<dim3(TOKENS / 128, MLPD / 128), 256, 0, stream>>>(
          shrd, wf1, EMB, MLPD, nullptr, nullptr, nullptr, big);
      gemm1_kernel<4><<<dim3(TOKENS / 128, EMB / 128), 256, 0, stream>>>(
          big, wf2, MLPD, EMB, nullptr, nullptr, nullptr, x);
    } else {
      for (int c = 0; c < NCH; ++c) {
        gemm1_kernel<3><<<dim3(CH / 128, MLPD / 128), 256, 0, stream>>>(
            shrd + (size_t)c * CH * EMB, wf1, EMB, MLPD, nullptr, nullptr, nullptr, big);
        gemm1_kernel<4><<<dim3(CH / 128, EMB / 128), 256, 0, stream>>>(
            big, wf2, MLPD, EMB, nullptr, nullptr, nullptr, x + (size_t)c * CH * EMB);
      }
    }
  }
  ln_kernel<1><<<TOKENS / 4, 256, 0, stream>>>(x, lnf_scale, lnf_bias,
                                               nullptr, (float*)d_out);
}